// Round 3
// baseline (182.831 us; speedup 1.0000x reference)
//
#include <hip/hip_runtime.h>
#include <cstdint>

#define IN_F   4096
#define OUT_F  4096
#define BS     64      // sparsity block size
#define NB     64      // blocks per weight dim
#define N_TOK  8192
#define TM     128     // token tile per workgroup
#define BK     64      // K-slice = one sparsity block

typedef __attribute__((ext_vector_type(8))) short          bf16x8;
typedef __attribute__((ext_vector_type(8))) unsigned short u16x8;
typedef __attribute__((ext_vector_type(4))) float          f32x4;

// ---------------- workspace layout (bytes) ----------------
#define WS_COUNTS_OFF  0ull
#define WS_COLS_OFF    256ull
#define WS_XT_OFF      32768ull                        // x tiles: [mt][kb] 32 KB each (hi plane 16K + lo plane 16K), pre-swizzled
#define WS_XT_BYTES    (4096ull * 32768ull)            // 134,217,728
#define WS_WT_OFF      (WS_XT_OFF + WS_XT_BYTES)       // w tiles: [br][slot] 16 KB each (hi 8K + lo 8K), pre-swizzled
#define WS_WT_BYTES    (4096ull * 16384ull)            // 67,108,864
#define WS_NEEDED      (WS_WT_OFF + WS_WT_BYTES)       // ~192 MiB

// ---------------------------------------------------------------------------
// Kernel 1: block-sparse metadata from the block-constant mask (deterministic)
// ---------------------------------------------------------------------------
__global__ void build_meta_kernel(const float* __restrict__ mask,
                                  int* __restrict__ counts,
                                  int* __restrict__ cols) {
    int br = blockIdx.x;
    int bc = threadIdx.x;
    float v = mask[(size_t)(br * BS) * IN_F + (size_t)bc * BS];
    unsigned long long ball = __ballot(v != 0.0f);
    if (v != 0.0f) {
        int pos = __popcll(ball & ((1ull << bc) - 1ull));
        cols[br * NB + pos] = bc;
    }
    if (bc == 0) counts[br] = __popcll(ball);
}

// split fp32 -> bf16 hi + bf16 lo (RNE both);  x ~= hi + lo, residual ~2^-17|x|
__device__ __forceinline__ void cvt_split8(const float* v, u16x8& hv, u16x8& lv) {
#pragma unroll
    for (int j = 0; j < 8; ++j) {
        unsigned u  = __float_as_uint(v[j]);
        unsigned r  = u + 0x7FFFu + ((u >> 16) & 1u);
        unsigned short h = (unsigned short)(r >> 16);
        float hf = __uint_as_float(((unsigned)h) << 16);
        float l  = v[j] - hf;
        unsigned ul = __float_as_uint(l);
        unsigned rl = ul + 0x7FFFu + ((ul >> 16) & 1u);
        hv[j] = h;
        lv[j] = (unsigned short)(rl >> 16);
    }
}

// ---------------------------------------------------------------------------
// Kernel 2a: convert x -> tile-ready, pre-swizzled bf16 hi/lo planes.
// Tile (mt,kb): u16 tile[2][128][64]; element (row, slot8) stored at
// slot' = slot ^ (row & 7)  (16B-slot XOR swizzle, matches GEMM ds_read).
// ---------------------------------------------------------------------------
__global__ __launch_bounds__(256)
void convert_x_kernel(const float* __restrict__ x, unsigned short* __restrict__ xt) {
    const int t  = blockIdx.x;          // 0..4095
    const int mt = t >> 6, kb = t & 63;
    unsigned short* tile = xt + (size_t)t * 16384;   // u16 units (32 KB)
#pragma unroll
    for (int l = 0; l < 4; ++l) {
        int g    = threadIdx.x + l * 256;            // 0..1023
        int row  = g >> 3, slot = g & 7;
        const float* src = x + (size_t)(mt * TM + row) * IN_F + kb * BK + slot * 8;
        float4 v0 = *(const float4*)src;
        float4 v1 = *(const float4*)(src + 4);
        float v[8] = {v0.x, v0.y, v0.z, v0.w, v1.x, v1.y, v1.z, v1.w};
        u16x8 hv, lv;
        cvt_split8(v, hv, lv);
        int dst = row * 64 + ((slot ^ (row & 7)) << 3);
        *(u16x8*)&tile[dst]        = hv;
        *(u16x8*)&tile[8192 + dst] = lv;
    }
}

// ---------------------------------------------------------------------------
// Kernel 2b: convert kept W blocks -> packed [br][slot] tiles, same swizzle.
// ---------------------------------------------------------------------------
__global__ __launch_bounds__(256)
void convert_w_kernel(const float* __restrict__ w,
                      const int* __restrict__ counts,
                      const int* __restrict__ cols,
                      unsigned short* __restrict__ wt) {
    const int br = blockIdx.y, si = blockIdx.x;
    if (si >= counts[br]) return;
    const int kb = cols[br * NB + si];
    unsigned short* tile = wt + (size_t)(br * NB + si) * 8192;   // u16 units (16 KB)
#pragma unroll
    for (int l = 0; l < 2; ++l) {
        int g    = threadIdx.x + l * 256;            // 0..511
        int row  = g >> 3, slot = g & 7;
        const float* src = w + (size_t)(br * BS + row) * IN_F + kb * BK + slot * 8;
        float4 v0 = *(const float4*)src;
        float4 v1 = *(const float4*)(src + 4);
        float v[8] = {v0.x, v0.y, v0.z, v0.w, v1.x, v1.y, v1.z, v1.w};
        u16x8 hv, lv;
        cvt_split8(v, hv, lv);
        int dst = row * 64 + ((slot ^ (row & 7)) << 3);
        *(u16x8*)&tile[dst]        = hv;
        *(u16x8*)&tile[4096 + dst] = lv;
    }
}

// async global->LDS, 16B per lane. LDS base wave-uniform; global per-lane.
__device__ __forceinline__ void gll16(const void* g, void* l) {
    __builtin_amdgcn_global_load_lds(
        (const __attribute__((address_space(1))) unsigned int*)g,
        (__attribute__((address_space(3))) unsigned int*)l, 16, 0, 0);
}

// ---------------------------------------------------------------------------
// Kernel 3: block-sparse GEMM from pre-converted tiles.
// WG 256 thr (4 waves), tile TM(128) x 64 outputs. Pure gll-stage + MFMA loop.
// ---------------------------------------------------------------------------
__global__ __launch_bounds__(256, 3)
void bsr_mfma2_kernel(const unsigned short* __restrict__ xt,
                      const unsigned short* __restrict__ wt,
                      const float* __restrict__ bias,
                      const int*   __restrict__ counts,
                      const int*   __restrict__ cols,
                      float* __restrict__ out) {
    __shared__ unsigned short xs[2 * TM * BK];   // 32 KB: hi plane, lo plane
    __shared__ unsigned short wsb[2 * BS * BK];  // 16 KB: hi plane, lo plane

    // XCD-chunked bijective swizzle: XCD x gets mts [x*8, x*8+8), br-fast,
    // so co-resident WGs on one XCD share the same mt's x tiles in its L2.
    const int xcd = blockIdx.x & 7;
    const int j   = blockIdx.x >> 3;          // 0..511
    const int mt  = xcd * 8 + (j >> 6);
    const int br  = j & 63;

    const int tid  = threadIdx.x;
    const int lane = tid & 63;
    const int wv   = tid >> 6;
    const int fr   = lane & 15;
    const int kg   = lane >> 4;

    const int  cnt  = counts[br];
    const int* colp = cols + br * NB;

    f32x4 acc[2][4];
#pragma unroll
    for (int a = 0; a < 2; ++a)
#pragma unroll
        for (int b = 0; b < 4; ++b) acc[a][b] = (f32x4)0.0f;

    for (int si = 0; si < cnt; ++si) {
        const int kb = colp[si];
        const char* xg = (const char*)(xt + (size_t)(mt * 64 + kb) * 16384);
        const char* wg = (const char*)(wt + (size_t)(br * 64 + si) * 8192);

        // ---- stage: wave wv covers its contiguous quarter of each region ----
        {
            const int bx = wv * 8192;             // bytes into 32 KB x tile
#pragma unroll
            for (int q = 0; q < 8; ++q)
                gll16(xg + bx + q * 1024 + lane * 16, (char*)xs + bx + q * 1024);
            const int bw = wv * 4096;             // bytes into 16 KB w tile
#pragma unroll
            for (int q = 0; q < 4; ++q)
                gll16(wg + bw + q * 1024 + lane * 16, (char*)wsb + bw + q * 1024);
        }
        __syncthreads();   // drains vmcnt -> LDS ready

        // ---- MFMA: 2 K-steps of 32; 3 split passes (hh, hl, lh) ----
#pragma unroll
        for (int ks = 0; ks < 2; ++ks) {
            bf16x8 ah[2], al[2], bh[4], bl[4];
#pragma unroll
            for (int mr = 0; mr < 2; ++mr) {
                int row  = wv * 32 + mr * 16 + fr;
                int off  = row * 64 + (((ks * 4 + kg) ^ (row & 7)) << 3);
                ah[mr] = *(const bf16x8*)&xs[off];
                al[mr] = *(const bf16x8*)&xs[8192 + off];
            }
#pragma unroll
            for (int nr = 0; nr < 4; ++nr) {
                int row  = nr * 16 + fr;
                int off  = row * 64 + (((ks * 4 + kg) ^ (row & 7)) << 3);
                bh[nr] = *(const bf16x8*)&wsb[off];
                bl[nr] = *(const bf16x8*)&wsb[4096 + off];
            }
#pragma unroll
            for (int mr = 0; mr < 2; ++mr)
#pragma unroll
                for (int nr = 0; nr < 4; ++nr) {
                    acc[mr][nr] = __builtin_amdgcn_mfma_f32_16x16x32_bf16(
                        ah[mr], bh[nr], acc[mr][nr], 0, 0, 0);
                    acc[mr][nr] = __builtin_amdgcn_mfma_f32_16x16x32_bf16(
                        ah[mr], bl[nr], acc[mr][nr], 0, 0, 0);
                    acc[mr][nr] = __builtin_amdgcn_mfma_f32_16x16x32_bf16(
                        al[mr], bh[nr], acc[mr][nr], 0, 0, 0);
                }
        }
        __syncthreads();   // before next stage overwrites LDS
    }

    // ---- epilogue: bias + fp32 stores.  C/D: col=lane&15, row=(lane>>4)*4+r ----
    const int mbase = mt * TM;
    const int obase = br * BS;
#pragma unroll
    for (int nr = 0; nr < 4; ++nr) {
        float bv = bias[obase + nr * 16 + fr];
#pragma unroll
        for (int mr = 0; mr < 2; ++mr) {
#pragma unroll
            for (int r = 0; r < 4; ++r) {
                int m = mbase + wv * 32 + mr * 16 + kg * 4 + r;
                out[(size_t)m * OUT_F + obase + nr * 16 + fr] = acc[mr][nr][r] + bv;
            }
        }
    }
}

// ---------------------------------------------------------------------------
// Fallback (round-2 kernel): in-loop conversion, used only if ws too small.
// ---------------------------------------------------------------------------
__global__ __launch_bounds__(256, 3)
void bsr_mfma_kernel(const float* __restrict__ x,
                     const float* __restrict__ w,
                     const float* __restrict__ bias,
                     const int*   __restrict__ counts,
                     const int*   __restrict__ cols,
                     float* __restrict__ out) {
    __shared__ unsigned short xs_hi[TM * BK];
    __shared__ unsigned short xs_lo[TM * BK];
    __shared__ unsigned short ws_hi[BS * BK];
    __shared__ unsigned short ws_lo[BS * BK];

    const int mt   = blockIdx.x;
    const int br   = blockIdx.y;
    const int tid  = threadIdx.x;
    const int lane = tid & 63;
    const int wv   = tid >> 6;
    const int fr   = lane & 15;
    const int kg   = lane >> 4;

    const int mbase = mt * TM;
    const int obase = br * BS;

    const int  cnt  = counts[br];
    const int* colp = cols + br * NB;

    f32x4 acc[2][4];
#pragma unroll
    for (int a = 0; a < 2; ++a)
#pragma unroll
        for (int b = 0; b < 4; ++b) acc[a][b] = (f32x4)0.0f;

    for (int kb = 0; kb < cnt; ++kb) {
        const int kbase = colp[kb] * BS;
#pragma unroll
        for (int l = 0; l < 4; ++l) {
            int g = tid + l * 256;
            int row = g >> 3, slot = g & 7;
            const float* src = x + (size_t)(mbase + row) * IN_F + kbase + slot * 8;
            float4 v0 = *(const float4*)(src);
            float4 v1 = *(const float4*)(src + 4);
            float v[8] = {v0.x, v0.y, v0.z, v0.w, v1.x, v1.y, v1.z, v1.w};
            u16x8 hv, lv;
            cvt_split8(v, hv, lv);
            int dst = row * BK + ((slot ^ (row & 7)) << 3);
            *(u16x8*)&xs_hi[dst] = hv;
            *(u16x8*)&xs_lo[dst] = lv;
        }
#pragma unroll
        for (int l = 0; l < 2; ++l) {
            int g = tid + l * 256;
            int row = g >> 3, slot = g & 7;
            const float* src = w + (size_t)(obase + row) * IN_F + kbase + slot * 8;
            float4 v0 = *(const float4*)(src);
            float4 v1 = *(const float4*)(src + 4);
            float v[8] = {v0.x, v0.y, v0.z, v0.w, v1.x, v1.y, v1.z, v1.w};
            u16x8 hv, lv;
            cvt_split8(v, hv, lv);
            int dst = row * BK + ((slot ^ (row & 7)) << 3);
            *(u16x8*)&ws_hi[dst] = hv;
            *(u16x8*)&ws_lo[dst] = lv;
        }
        __syncthreads();
#pragma unroll
        for (int ks = 0; ks < 2; ++ks) {
            bf16x8 ah[2], al[2], bh[4], bl[4];
#pragma unroll
            for (int mr = 0; mr < 2; ++mr) {
                int row  = wv * 32 + mr * 16 + fr;
                int off  = row * BK + (((ks * 4 + kg) ^ (row & 7)) << 3);
                ah[mr] = *(bf16x8*)&xs_hi[off];
                al[mr] = *(bf16x8*)&xs_lo[off];
            }
#pragma unroll
            for (int nr = 0; nr < 4; ++nr) {
                int row  = nr * 16 + fr;
                int off  = row * BK + (((ks * 4 + kg) ^ (row & 7)) << 3);
                bh[nr] = *(bf16x8*)&ws_hi[off];
                bl[nr] = *(bf16x8*)&ws_lo[off];
            }
#pragma unroll
            for (int mr = 0; mr < 2; ++mr)
#pragma unroll
                for (int nr = 0; nr < 4; ++nr) {
                    acc[mr][nr] = __builtin_amdgcn_mfma_f32_16x16x32_bf16(
                        ah[mr], bh[nr], acc[mr][nr], 0, 0, 0);
                    acc[mr][nr] = __builtin_amdgcn_mfma_f32_16x16x32_bf16(
                        ah[mr], bl[nr], acc[mr][nr], 0, 0, 0);
                    acc[mr][nr] = __builtin_amdgcn_mfma_f32_16x16x32_bf16(
                        al[mr], bh[nr], acc[mr][nr], 0, 0, 0);
                }
        }
        __syncthreads();
    }

#pragma unroll
    for (int nr = 0; nr < 4; ++nr) {
        float bv = bias[obase + nr * 16 + fr];
#pragma unroll
        for (int mr = 0; mr < 2; ++mr) {
#pragma unroll
            for (int r = 0; r < 4; ++r) {
                int m = mbase + wv * 32 + mr * 16 + kg * 4 + r;
                out[(size_t)m * OUT_F + obase + nr * 16 + fr] = acc[mr][nr][r] + bv;
            }
        }
    }
}

extern "C" void kernel_launch(void* const* d_in, const int* in_sizes, int n_in,
                              void* d_out, int out_size, void* d_ws, size_t ws_size,
                              hipStream_t stream) {
    const float* x    = (const float*)d_in[0];
    const float* w    = (const float*)d_in[1];
    const float* bias = (const float*)d_in[2];
    const float* mask = (const float*)d_in[3];
    float* out = (float*)d_out;

    int* counts = (int*)((char*)d_ws + WS_COUNTS_OFF);
    int* cols   = (int*)((char*)d_ws + WS_COLS_OFF);

    build_meta_kernel<<<NB, 64, 0, stream>>>(mask, counts, cols);

    if (ws_size >= WS_NEEDED) {
        unsigned short* xt = (unsigned short*)((char*)d_ws + WS_XT_OFF);
        unsigned short* wt = (unsigned short*)((char*)d_ws + WS_WT_OFF);
        convert_x_kernel<<<4096, 256, 0, stream>>>(x, xt);
        convert_w_kernel<<<dim3(NB, NB), 256, 0, stream>>>(w, counts, cols, wt);
        bsr_mfma2_kernel<<<4096, 256, 0, stream>>>(xt, wt, bias, counts, cols, out);
    } else {
        dim3 grid(N_TOK / TM, NB);
        bsr_mfma_kernel<<<grid, 256, 0, stream>>>(x, w, bias, counts, cols, out);
    }
}

// Round 4
// 119.446 us; speedup vs baseline: 1.5307x; 1.5307x over previous
//
#include <hip/hip_runtime.h>
#include <hip/hip_fp16.h>
#include <cstdint>

#define IN_F   4096
#define OUT_F  4096
#define BS     64      // sparsity block size
#define NB     64      // blocks per weight dim
#define N_TOK  8192
#define TM     128     // token tile per workgroup
#define BK     64      // K-slice = one sparsity block

typedef __attribute__((ext_vector_type(8))) _Float16       f16x8;
typedef __attribute__((ext_vector_type(8))) unsigned short u16x8;
typedef __attribute__((ext_vector_type(4))) float          f32x4;

// ---------------- workspace layout (bytes) ----------------
// counts[64] @0, cols[64*64] @256
// xt: 4096 tiles (mt,kb) x 16 KB  (u16[128][64], pre-swizzled)  @ 32768
// wt: 4096 slots (br,si) x 8 KB   (u16[64][64],  pre-swizzled)
#define WS_XT_OFF      32768ull
#define WS_XT_BYTES    (4096ull * 16384ull)            // 64 MiB
#define WS_WT_OFF      (WS_XT_OFF + WS_XT_BYTES)
#define WS_WT_BYTES    (4096ull * 8192ull)             // 32 MiB
#define WS_NEEDED      (WS_WT_OFF + WS_WT_BYTES)       // ~96 MiB

// ---------------------------------------------------------------------------
// Kernel 1: block-sparse metadata from the block-constant mask (deterministic)
// ---------------------------------------------------------------------------
__global__ void build_meta_kernel(const float* __restrict__ mask,
                                  int* __restrict__ counts,
                                  int* __restrict__ cols) {
    int br = blockIdx.x;
    int bc = threadIdx.x;
    float v = mask[(size_t)(br * BS) * IN_F + (size_t)bc * BS];
    unsigned long long ball = __ballot(v != 0.0f);
    if (v != 0.0f) {
        int pos = __popcll(ball & ((1ull << bc) - 1ull));
        cols[br * NB + pos] = bc;
    }
    if (bc == 0) counts[br] = __popcll(ball);
}

// fp32x8 -> fp16x8 (RNE)
__device__ __forceinline__ u16x8 cvt_f16x8(const float* v) {
    u16x8 o;
#pragma unroll
    for (int j = 0; j < 8; ++j)
        o[j] = __half_as_ushort(__float2half_rn(v[j]));
    return o;
}

// ---------------------------------------------------------------------------
// Kernel 2a: x -> tile-ready pre-swizzled fp16. Tile (mt,kb): u16[128][64];
// (row, slot8) stored at slot' = slot ^ (row & 7)   (16B-slot XOR swizzle)
// ---------------------------------------------------------------------------
__global__ __launch_bounds__(256)
void convert_x_kernel(const float* __restrict__ x, unsigned short* __restrict__ xt) {
    const int t  = blockIdx.x;          // 0..4095
    const int mt = t >> 6, kb = t & 63;
    unsigned short* tile = xt + (size_t)t * 8192;
#pragma unroll
    for (int l = 0; l < 4; ++l) {
        int g    = threadIdx.x + l * 256;            // 0..1023
        int row  = g >> 3, slot = g & 7;
        const float* src = x + (size_t)(mt * TM + row) * IN_F + kb * BK + slot * 8;
        float4 v0 = *(const float4*)src;
        float4 v1 = *(const float4*)(src + 4);
        float v[8] = {v0.x, v0.y, v0.z, v0.w, v1.x, v1.y, v1.z, v1.w};
        *(u16x8*)&tile[row * 64 + ((slot ^ (row & 7)) << 3)] = cvt_f16x8(v);
    }
}

// ---------------------------------------------------------------------------
// Kernel 2b: kept W blocks -> packed [br][si] fp16 tiles, same swizzle.
// ---------------------------------------------------------------------------
__global__ __launch_bounds__(256)
void convert_w_kernel(const float* __restrict__ w,
                      const int* __restrict__ counts,
                      const int* __restrict__ cols,
                      unsigned short* __restrict__ wt) {
    const int br = blockIdx.y, si = blockIdx.x;
    if (si >= counts[br]) return;
    const int kb = cols[br * NB + si];
    unsigned short* tile = wt + (size_t)(br * NB + si) * 4096;
#pragma unroll
    for (int l = 0; l < 2; ++l) {
        int g    = threadIdx.x + l * 256;            // 0..511
        int row  = g >> 3, slot = g & 7;
        const float* src = w + (size_t)(br * BS + row) * IN_F + kb * BK + slot * 8;
        float4 v0 = *(const float4*)src;
        float4 v1 = *(const float4*)(src + 4);
        float v[8] = {v0.x, v0.y, v0.z, v0.w, v1.x, v1.y, v1.z, v1.w};
        *(u16x8*)&tile[row * 64 + ((slot ^ (row & 7)) << 3)] = cvt_f16x8(v);
    }
}

// async global->LDS, 16B per lane. LDS base wave-uniform; global per-lane.
__device__ __forceinline__ void gll16(const void* g, void* l) {
    __builtin_amdgcn_global_load_lds(
        (const __attribute__((address_space(1))) unsigned int*)g,
        (__attribute__((address_space(3))) unsigned int*)l, 16, 0, 0);
}

// ---------------------------------------------------------------------------
// Kernel 3: block-sparse GEMM, fp16 single-pass MFMA, 2-phase LDS dbuf.
// WG 256 thr (4 waves), tile TM(128) x 64 outputs.
// ---------------------------------------------------------------------------
__global__ __launch_bounds__(256, 3)
void bsr_mfma3_kernel(const unsigned short* __restrict__ xt,
                      const unsigned short* __restrict__ wt,
                      const float* __restrict__ bias,
                      const int*   __restrict__ counts,
                      const int*   __restrict__ cols,
                      float* __restrict__ out) {
    __shared__ unsigned short xs[2][TM * BK];   // 2 x 16 KB
    __shared__ unsigned short wsb[2][BS * BK];  // 2 x  8 KB

    // XCD-chunked bijective swizzle: XCD x owns mts [x*8, x*8+8), br-fast.
    const int xcd = blockIdx.x & 7;
    const int j   = blockIdx.x >> 3;          // 0..511
    const int mt  = xcd * 8 + (j >> 6);
    const int br  = j & 63;

    const int tid  = threadIdx.x;
    const int lane = tid & 63;
    const int wv   = tid >> 6;
    const int fr   = lane & 15;
    const int kg   = lane >> 4;

    const int  cnt  = counts[br];
    const int* colp = cols + br * NB;

    f32x4 acc[2][4];
#pragma unroll
    for (int a = 0; a < 2; ++a)
#pragma unroll
        for (int b = 0; b < 4; ++b) acc[a][b] = (f32x4)0.0f;

    const char* xbase = (const char*)xt;
    const char* wbase = (const char*)wt;

    // stage tile si into buffer bb: wave wv covers its contiguous quarter
    auto stage = [&](int si, int bb) {
        const int kb = colp[si];
        const char* xg = xbase + ((size_t)(mt * 64 + kb) << 14);   // 16 KB tiles
        const char* wg = wbase + ((size_t)(br * 64 + si) << 13);   //  8 KB tiles
        const int bx = wv * 4096;
#pragma unroll
        for (int q = 0; q < 4; ++q)
            gll16(xg + bx + q * 1024 + lane * 16, (char*)xs[bb] + bx + q * 1024);
        const int bw = wv * 2048;
#pragma unroll
        for (int q = 0; q < 2; ++q)
            gll16(wg + bw + q * 1024 + lane * 16, (char*)wsb[bb] + bw + q * 1024);
    };

    int cur = 0;
    if (cnt > 0) stage(0, 0);
    __syncthreads();

    for (int si = 0; si < cnt; ++si) {
        if (si + 1 < cnt) stage(si + 1, cur ^ 1);   // overlap with compute(cur)

#pragma unroll
        for (int ks = 0; ks < 2; ++ks) {
            f16x8 a[2], b[4];
#pragma unroll
            for (int mr = 0; mr < 2; ++mr) {
                int row = wv * 32 + mr * 16 + fr;
                a[mr] = *(const f16x8*)&xs[cur][row * 64 + (((ks * 4 + kg) ^ (row & 7)) << 3)];
            }
#pragma unroll
            for (int nr = 0; nr < 4; ++nr) {
                int row = nr * 16 + fr;
                b[nr] = *(const f16x8*)&wsb[cur][row * 64 + (((ks * 4 + kg) ^ (row & 7)) << 3)];
            }
#pragma unroll
            for (int mr = 0; mr < 2; ++mr)
#pragma unroll
                for (int nr = 0; nr < 4; ++nr)
                    acc[mr][nr] = __builtin_amdgcn_mfma_f32_16x16x32_f16(
                        a[mr], b[nr], acc[mr][nr], 0, 0, 0);
        }
        __syncthreads();   // drains next-tile stage; all waves done reading cur
        cur ^= 1;
    }

    // ---- epilogue: bias + fp32 stores.  C/D: col=lane&15, row=(lane>>4)*4+r ----
    const int mbase = mt * TM;
    const int obase = br * BS;
#pragma unroll
    for (int nr = 0; nr < 4; ++nr) {
        float bv = bias[obase + nr * 16 + fr];
#pragma unroll
        for (int mr = 0; mr < 2; ++mr) {
#pragma unroll
            for (int r = 0; r < 4; ++r) {
                int m = mbase + wv * 32 + mr * 16 + kg * 4 + r;
                out[(size_t)m * OUT_F + obase + nr * 16 + fr] = acc[mr][nr][r] + bv;
            }
        }
    }
}

// ---------------------------------------------------------------------------
// Fallback (ws too small): fused in-loop fp16 conversion, single buffer.
// ---------------------------------------------------------------------------
__global__ __launch_bounds__(256, 3)
void bsr_fused_kernel(const float* __restrict__ x,
                      const float* __restrict__ w,
                      const float* __restrict__ bias,
                      const int*   __restrict__ counts,
                      const int*   __restrict__ cols,
                      float* __restrict__ out) {
    __shared__ unsigned short xs[TM * BK];
    __shared__ unsigned short wsb[BS * BK];

    const int mt   = blockIdx.x;
    const int br   = blockIdx.y;
    const int tid  = threadIdx.x;
    const int lane = tid & 63;
    const int wv   = tid >> 6;
    const int fr   = lane & 15;
    const int kg   = lane >> 4;

    const int mbase = mt * TM;
    const int obase = br * BS;
    const int  cnt  = counts[br];
    const int* colp = cols + br * NB;

    f32x4 acc[2][4];
#pragma unroll
    for (int a = 0; a < 2; ++a)
#pragma unroll
        for (int b = 0; b < 4; ++b) acc[a][b] = (f32x4)0.0f;

    for (int si = 0; si < cnt; ++si) {
        const int kbase = colp[si] * BS;
#pragma unroll
        for (int l = 0; l < 4; ++l) {
            int g = tid + l * 256;
            int row = g >> 3, slot = g & 7;
            const float* src = x + (size_t)(mbase + row) * IN_F + kbase + slot * 8;
            float4 v0 = *(const float4*)src;
            float4 v1 = *(const float4*)(src + 4);
            float v[8] = {v0.x, v0.y, v0.z, v0.w, v1.x, v1.y, v1.z, v1.w};
            *(u16x8*)&xs[row * BK + ((slot ^ (row & 7)) << 3)] = cvt_f16x8(v);
        }
#pragma unroll
        for (int l = 0; l < 2; ++l) {
            int g = tid + l * 256;
            int row = g >> 3, slot = g & 7;
            const float* src = w + (size_t)(obase + row) * IN_F + kbase + slot * 8;
            float4 v0 = *(const float4*)src;
            float4 v1 = *(const float4*)(src + 4);
            float v[8] = {v0.x, v0.y, v0.z, v0.w, v1.x, v1.y, v1.z, v1.w};
            *(u16x8*)&wsb[row * BK + ((slot ^ (row & 7)) << 3)] = cvt_f16x8(v);
        }
        __syncthreads();
#pragma unroll
        for (int ks = 0; ks < 2; ++ks) {
            f16x8 a[2], b[4];
#pragma unroll
            for (int mr = 0; mr < 2; ++mr) {
                int row = wv * 32 + mr * 16 + fr;
                a[mr] = *(const f16x8*)&xs[row * BK + (((ks * 4 + kg) ^ (row & 7)) << 3)];
            }
#pragma unroll
            for (int nr = 0; nr < 4; ++nr) {
                int row = nr * 16 + fr;
                b[nr] = *(const f16x8*)&wsb[row * BK + (((ks * 4 + kg) ^ (row & 7)) << 3)];
            }
#pragma unroll
            for (int mr = 0; mr < 2; ++mr)
#pragma unroll
                for (int nr = 0; nr < 4; ++nr)
                    acc[mr][nr] = __builtin_amdgcn_mfma_f32_16x16x32_f16(
                        a[mr], b[nr], acc[mr][nr], 0, 0, 0);
        }
        __syncthreads();
    }

#pragma unroll
    for (int nr = 0; nr < 4; ++nr) {
        float bv = bias[obase + nr * 16 + fr];
#pragma unroll
        for (int mr = 0; mr < 2; ++mr) {
#pragma unroll
            for (int r = 0; r < 4; ++r) {
                int m = mbase + wv * 32 + mr * 16 + kg * 4 + r;
                out[(size_t)m * OUT_F + obase + nr * 16 + fr] = acc[mr][nr][r] + bv;
            }
        }
    }
}

extern "C" void kernel_launch(void* const* d_in, const int* in_sizes, int n_in,
                              void* d_out, int out_size, void* d_ws, size_t ws_size,
                              hipStream_t stream) {
    const float* x    = (const float*)d_in[0];
    const float* w    = (const float*)d_in[1];
    const float* bias = (const float*)d_in[2];
    const float* mask = (const float*)d_in[3];
    float* out = (float*)d_out;

    int* counts = (int*)d_ws;
    int* cols   = (int*)((char*)d_ws + 256);

    build_meta_kernel<<<NB, 64, 0, stream>>>(mask, counts, cols);

    if (ws_size >= WS_NEEDED) {
        unsigned short* xt = (unsigned short*)((char*)d_ws + WS_XT_OFF);
        unsigned short* wt = (unsigned short*)((char*)d_ws + WS_WT_OFF);
        convert_x_kernel<<<4096, 256, 0, stream>>>(x, xt);
        convert_w_kernel<<<dim3(NB, NB), 256, 0, stream>>>(w, counts, cols, wt);
        bsr_mfma3_kernel<<<4096, 256, 0, stream>>>(xt, wt, bias, counts, cols, out);
    } else {
        dim3 grid(N_TOK / TM, NB);
        bsr_fused_kernel<<<grid, 256, 0, stream>>>(x, w, bias, counts, cols, out);
    }
}

// Round 6
// 113.895 us; speedup vs baseline: 1.6053x; 1.0487x over previous
//
#include <hip/hip_runtime.h>
#include <hip/hip_fp16.h>
#include <cstdint>

#define IN_F   4096
#define OUT_F  4096
#define BS     64      // sparsity block size
#define NB     64      // blocks per weight dim
#define N_TOK  8192
#define TM     256     // token tile per workgroup (4 waves x 64 rows)
#define BK     64      // K-slice = one sparsity block
#define NMT    (N_TOK / TM)   // 32 token tiles

typedef __attribute__((ext_vector_type(8))) _Float16       f16x8;
typedef __attribute__((ext_vector_type(8))) unsigned short u16x8;
typedef __attribute__((ext_vector_type(4))) float          f32x4;

// ---------------- workspace layout (bytes) ----------------
// counts[64] @0, cols[64*64] @256
// xt: 2048 tiles (mt,kb) x 32 KB  (u16[256][64], pre-swizzled)
// wt: 4096 slots (br,si) x 8 KB   (u16[64][64],  pre-swizzled)
#define WS_XT_OFF      32768ull
#define WS_XT_BYTES    (2048ull * 32768ull)            // 64 MiB
#define WS_WT_OFF      (WS_XT_OFF + WS_XT_BYTES)
#define WS_WT_BYTES    (4096ull * 8192ull)             // 32 MiB
#define WS_NEEDED      (WS_WT_OFF + WS_WT_BYTES)       // ~96 MiB

// ---------------------------------------------------------------------------
// Kernel 1: block-sparse metadata from the block-constant mask (deterministic)
// ---------------------------------------------------------------------------
__global__ void build_meta_kernel(const float* __restrict__ mask,
                                  int* __restrict__ counts,
                                  int* __restrict__ cols) {
    int br = blockIdx.x;
    int bc = threadIdx.x;
    float v = mask[(size_t)(br * BS) * IN_F + (size_t)bc * BS];
    unsigned long long ball = __ballot(v != 0.0f);
    if (v != 0.0f) {
        int pos = __popcll(ball & ((1ull << bc) - 1ull));
        cols[br * NB + pos] = bc;
    }
    if (bc == 0) counts[br] = __popcll(ball);
}

// fp32x8 -> fp16x8 (RNE)
__device__ __forceinline__ u16x8 cvt_f16x8(const float* v) {
    u16x8 o;
#pragma unroll
    for (int j = 0; j < 8; ++j)
        o[j] = __half_as_ushort(__float2half_rn(v[j]));
    return o;
}

// ---------------------------------------------------------------------------
// Kernel 2a: x -> tile-ready pre-swizzled fp16. Tile (mt,kb): u16[256][64];
// (row, slot8) stored at slot' = slot ^ (row & 7)   (16B-slot XOR swizzle)
// ---------------------------------------------------------------------------
__global__ __launch_bounds__(256)
void convert_x_kernel(const float* __restrict__ x, unsigned short* __restrict__ xt) {
    const int t  = blockIdx.x;          // 0..2047
    const int mt = t >> 6, kb = t & 63;
    unsigned short* tile = xt + (size_t)t * 16384;   // u16 units (32 KB)
#pragma unroll
    for (int l = 0; l < 8; ++l) {
        int g    = threadIdx.x + l * 256;            // 0..2047
        int row  = g >> 3, slot = g & 7;
        const float* src = x + (size_t)(mt * TM + row) * IN_F + kb * BK + slot * 8;
        float4 v0 = *(const float4*)src;
        float4 v1 = *(const float4*)(src + 4);
        float v[8] = {v0.x, v0.y, v0.z, v0.w, v1.x, v1.y, v1.z, v1.w};
        *(u16x8*)&tile[row * 64 + ((slot ^ (row & 7)) << 3)] = cvt_f16x8(v);
    }
}

// ---------------------------------------------------------------------------
// Kernel 2b: kept W blocks -> packed [br][si] fp16 tiles, same swizzle.
// ---------------------------------------------------------------------------
__global__ __launch_bounds__(256)
void convert_w_kernel(const float* __restrict__ w,
                      const int* __restrict__ counts,
                      const int* __restrict__ cols,
                      unsigned short* __restrict__ wt) {
    const int br = blockIdx.y, si = blockIdx.x;
    if (si >= counts[br]) return;
    const int kb = cols[br * NB + si];
    unsigned short* tile = wt + (size_t)(br * NB + si) * 4096;
#pragma unroll
    for (int l = 0; l < 2; ++l) {
        int g    = threadIdx.x + l * 256;            // 0..511
        int row  = g >> 3, slot = g & 7;
        const float* src = w + (size_t)(br * BS + row) * IN_F + kb * BK + slot * 8;
        float4 v0 = *(const float4*)src;
        float4 v1 = *(const float4*)(src + 4);
        float v[8] = {v0.x, v0.y, v0.z, v0.w, v1.x, v1.y, v1.z, v1.w};
        *(u16x8*)&tile[row * 64 + ((slot ^ (row & 7)) << 3)] = cvt_f16x8(v);
    }
}

// async global->LDS, 16B per lane. LDS base wave-uniform; global per-lane.
__device__ __forceinline__ void gll16(const void* g, void* l) {
    __builtin_amdgcn_global_load_lds(
        (const __attribute__((address_space(1))) unsigned int*)g,
        (__attribute__((address_space(3))) unsigned int*)l, 16, 0, 0);
}

// ---------------------------------------------------------------------------
// Kernel 3: block-sparse GEMM, fp16 MFMA, TM=256, wave tile 64x64 (4x4 rep),
// 2-phase LDS double-buffer.
// ---------------------------------------------------------------------------
__global__ __launch_bounds__(256, 2)
void bsr_mfma4_kernel(const unsigned short* __restrict__ xt,
                      const unsigned short* __restrict__ wt,
                      const float* __restrict__ bias,
                      const int*   __restrict__ counts,
                      const int*   __restrict__ cols,
                      float* __restrict__ out) {
    __shared__ unsigned short xs[2][TM * BK];   // 2 x 32 KB
    __shared__ unsigned short wsb[2][BS * BK];  // 2 x  8 KB

    // XCD-chunked bijective swizzle (2048 % 8 == 0): XCD x owns mts
    // [x*4, x*4+4), br-fast -> per-XCD xt working set ~2 MB fits its L2.
    const int xcd = blockIdx.x & 7;
    const int j   = blockIdx.x >> 3;          // 0..255
    const int mt  = xcd * 4 + (j >> 6);
    const int br  = j & 63;

    const int tid  = threadIdx.x;
    const int lane = tid & 63;
    const int wv   = tid >> 6;        // wave id 0..3 -> rows [wv*64, wv*64+64)
    const int fr   = lane & 15;
    const int kg   = lane >> 4;

    const int  cnt  = counts[br];
    const int* colp = cols + br * NB;

    f32x4 acc[4][4];
#pragma unroll
    for (int a = 0; a < 4; ++a)
#pragma unroll
        for (int b = 0; b < 4; ++b) acc[a][b] = (f32x4)0.0f;

    const char* xbase = (const char*)xt;
    const char* wbase = (const char*)wt;

    // stage tile si into buffer bb: wave wv covers its contiguous quarter
    auto stage = [&](int si, int bb) {
        const int kb = colp[si];
        const char* xg = xbase + ((size_t)(mt * 64 + kb) << 15);   // 32 KB tiles
        const char* wg = wbase + ((size_t)(br * 64 + si) << 13);   //  8 KB tiles
        const int bx = wv * 8192;
#pragma unroll
        for (int q = 0; q < 8; ++q)
            gll16(xg + bx + q * 1024 + lane * 16, (char*)xs[bb] + bx + q * 1024);
        const int bw = wv * 2048;
#pragma unroll
        for (int q = 0; q < 2; ++q)
            gll16(wg + bw + q * 1024 + lane * 16, (char*)wsb[bb] + bw + q * 1024);
    };

    int cur = 0;
    if (cnt > 0) stage(0, 0);
    __syncthreads();

    for (int si = 0; si < cnt; ++si) {
        if (si + 1 < cnt) stage(si + 1, cur ^ 1);   // overlap with compute(cur)

#pragma unroll
        for (int ks = 0; ks < 2; ++ks) {
            f16x8 a[4], b[4];
#pragma unroll
            for (int mr = 0; mr < 4; ++mr) {
                int row = wv * 64 + mr * 16 + fr;
                a[mr] = *(const f16x8*)&xs[cur][row * 64 + (((ks * 4 + kg) ^ (row & 7)) << 3)];
            }
#pragma unroll
            for (int nr = 0; nr < 4; ++nr) {
                int row = nr * 16 + fr;
                b[nr] = *(const f16x8*)&wsb[cur][row * 64 + (((ks * 4 + kg) ^ (row & 7)) << 3)];
            }
#pragma unroll
            for (int mr = 0; mr < 4; ++mr)
#pragma unroll
                for (int nr = 0; nr < 4; ++nr)
                    acc[mr][nr] = __builtin_amdgcn_mfma_f32_16x16x32_f16(
                        a[mr], b[nr], acc[mr][nr], 0, 0, 0);
        }
        __syncthreads();   // all waves done reading cur; next stage drained
        cur ^= 1;
    }

    // ---- epilogue: bias + fp32 stores.  C/D: col=lane&15, row=(lane>>4)*4+r ----
    const int mbase = mt * TM;
    const int obase = br * BS;
#pragma unroll
    for (int nr = 0; nr < 4; ++nr) {
        float bv = bias[obase + nr * 16 + fr];
#pragma unroll
        for (int mr = 0; mr < 4; ++mr) {
#pragma unroll
            for (int r = 0; r < 4; ++r) {
                int m = mbase + wv * 64 + mr * 16 + kg * 4 + r;
                out[(size_t)m * OUT_F + obase + nr * 16 + fr] = acc[mr][nr][r] + bv;
            }
        }
    }
}

// ---------------------------------------------------------------------------
// Fallback (ws too small): fused in-loop fp16 conversion, single buffer.
// ---------------------------------------------------------------------------
__global__ __launch_bounds__(256, 3)
void bsr_fused_kernel(const float* __restrict__ x,
                      const float* __restrict__ w,
                      const float* __restrict__ bias,
                      const int*   __restrict__ counts,
                      const int*   __restrict__ cols,
                      float* __restrict__ out) {
    __shared__ unsigned short xs[128 * BK];
    __shared__ unsigned short wsb[BS * BK];

    const int mt   = blockIdx.x;
    const int br   = blockIdx.y;
    const int tid  = threadIdx.x;
    const int lane = tid & 63;
    const int wv   = tid >> 6;
    const int fr   = lane & 15;
    const int kg   = lane >> 4;

    const int mbase = mt * 128;
    const int obase = br * BS;
    const int  cnt  = counts[br];
    const int* colp = cols + br * NB;

    f32x4 acc[2][4];
#pragma unroll
    for (int a = 0; a < 2; ++a)
#pragma unroll
        for (int b = 0; b < 4; ++b) acc[a][b] = (f32x4)0.0f;

    for (int si = 0; si < cnt; ++si) {
        const int kbase = colp[si] * BS;
#pragma unroll
        for (int l = 0; l < 4; ++l) {
            int g = tid + l * 256;
            int row = g >> 3, slot = g & 7;
            const float* src = x + (size_t)(mbase + row) * IN_F + kbase + slot * 8;
            float4 v0 = *(const float4*)src;
            float4 v1 = *(const float4*)(src + 4);
            float v[8] = {v0.x, v0.y, v0.z, v0.w, v1.x, v1.y, v1.z, v1.w};
            *(u16x8*)&xs[row * BK + ((slot ^ (row & 7)) << 3)] = cvt_f16x8(v);
        }
#pragma unroll
        for (int l = 0; l < 2; ++l) {
            int g = tid + l * 256;
            int row = g >> 3, slot = g & 7;
            const float* src = w + (size_t)(obase + row) * IN_F + kbase + slot * 8;
            float4 v0 = *(const float4*)src;
            float4 v1 = *(const float4*)(src + 4);
            float v[8] = {v0.x, v0.y, v0.z, v0.w, v1.x, v1.y, v1.z, v1.w};
            *(u16x8*)&wsb[row * BK + ((slot ^ (row & 7)) << 3)] = cvt_f16x8(v);
        }
        __syncthreads();
#pragma unroll
        for (int ks = 0; ks < 2; ++ks) {
            f16x8 a[2], b[4];
#pragma unroll
            for (int mr = 0; mr < 2; ++mr) {
                int row = wv * 32 + mr * 16 + fr;
                a[mr] = *(const f16x8*)&xs[row * BK + (((ks * 4 + kg) ^ (row & 7)) << 3)];
            }
#pragma unroll
            for (int nr = 0; nr < 4; ++nr) {
                int row = nr * 16 + fr;
                b[nr] = *(const f16x8*)&wsb[row * BK + (((ks * 4 + kg) ^ (row & 7)) << 3)];
            }
#pragma unroll
            for (int mr = 0; mr < 2; ++mr)
#pragma unroll
                for (int nr = 0; nr < 4; ++nr)
                    acc[mr][nr] = __builtin_amdgcn_mfma_f32_16x16x32_f16(
                        a[mr], b[nr], acc[mr][nr], 0, 0, 0);
        }
        __syncthreads();
    }

#pragma unroll
    for (int nr = 0; nr < 4; ++nr) {
        float bv = bias[obase + nr * 16 + fr];
#pragma unroll
        for (int mr = 0; mr < 2; ++mr) {
#pragma unroll
            for (int r = 0; r < 4; ++r) {
                int m = mbase + wv * 32 + mr * 16 + kg * 4 + r;
                out[(size_t)m * OUT_F + obase + nr * 16 + fr] = acc[mr][nr][r] + bv;
            }
        }
    }
}

extern "C" void kernel_launch(void* const* d_in, const int* in_sizes, int n_in,
                              void* d_out, int out_size, void* d_ws, size_t ws_size,
                              hipStream_t stream) {
    const float* x    = (const float*)d_in[0];
    const float* w    = (const float*)d_in[1];
    const float* bias = (const float*)d_in[2];
    const float* mask = (const float*)d_in[3];
    float* out = (float*)d_out;

    int* counts = (int*)d_ws;
    int* cols   = (int*)((char*)d_ws + 256);

    build_meta_kernel<<<NB, 64, 0, stream>>>(mask, counts, cols);

    if (ws_size >= WS_NEEDED) {
        unsigned short* xt = (unsigned short*)((char*)d_ws + WS_XT_OFF);
        unsigned short* wt = (unsigned short*)((char*)d_ws + WS_WT_OFF);
        convert_x_kernel<<<NMT * NB, 256, 0, stream>>>(x, xt);
        convert_w_kernel<<<dim3(NB, NB), 256, 0, stream>>>(w, counts, cols, wt);
        bsr_mfma4_kernel<<<NMT * NB, 256, 0, stream>>>(xt, wt, bias, counts, cols, out);
    } else {
        dim3 grid(N_TOK / 128, NB);
        bsr_fused_kernel<<<grid, 256, 0, stream>>>(x, w, bias, counts, cols, out);
    }
}